// Round 9
// baseline (257.714 us; speedup 1.0000x reference)
//
#include <hip/hip_runtime.h>
#include <cstddef>

#define IN_CH 1024
#define NT    81
#define KGRID 7
#define NBINS 49
#define HH    100
#define WW    100
#define NPIX  (HH*WW)
#define NREG  1024
#define COLB  82            // gemm/pool column group per bin: 81 real + 1 pad (even)
#define NCOL  (NBINS*COLB)  // 4018 columns
#define NPADW 4096          // 32 N-tiles of 128 (multiple of 8 XCDs)
#define SROW  NCOL          // sm row stride
#define NG    8             // pool tap-groups per region (8*98 = 784)
#define BK    64            // K-tile (16 iters of K=1024; halves barrier count)
#define PXB   ((NPIX + 31) / 32)        // 313 prep_x col-blocks
#define PXG   (PXB * (IN_CH / 128))     // 2504 prep_x blocks
#define PREPG (PXG + NPADW)             // + 4096 prep_w blocks

typedef unsigned short ushortT;
typedef short bf16x8 __attribute__((ext_vector_type(8)));
typedef float f32x4  __attribute__((ext_vector_type(4)));

static __device__ __forceinline__ unsigned short f2bf(float f) {
    unsigned int u = __builtin_bit_cast(unsigned int, f);
    return (unsigned short)((u + 0x7fffu + ((u >> 16) & 1u)) >> 16);
}
static __device__ __forceinline__ float bf_lo(unsigned int v) {
    return __builtin_bit_cast(float, v << 16);
}
static __device__ __forceinline__ float bf_hi(unsigned int v) {
    return __builtin_bit_cast(float, v & 0xffff0000u);
}

// async global->LDS, 16B per lane; LDS dest = wave-uniform base + lane*16
static __device__ __forceinline__ void gld_lds16(const ushortT* g, ushortT* l) {
    __builtin_amdgcn_global_load_lds(
        (__attribute__((address_space(1))) void*)(unsigned long long)(uintptr_t)g,
        (__attribute__((address_space(3))) void*)(unsigned int)(unsigned long long)(uintptr_t)l,
        16, 0, 0);
}

// ---------- fused prep: x (C,P) fp32 -> xbT (P,C) bf16  |  conv_w -> Wr -------------
__global__ __launch_bounds__(256) void prep_fused(const float* __restrict__ x,
                                                  ushortT* __restrict__ xbT,
                                                  const float* __restrict__ conv_w,
                                                  ushortT* __restrict__ Wr) {
    __shared__ float tile[128][33];
    const int tid = threadIdx.x;
    const int bid = blockIdx.x;
    if (bid < PXG) {
        // ---- prep_x part: 32 pix x 128 ch transpose+cast, 16B stores ----
        const int p0 = (bid % PXB) * 32;
        const int c0 = (bid / PXB) * 128;
        const int pl = tid & 31;
        const int cg = tid >> 5;          // 0..7
        const int p = p0 + pl;
#pragma unroll
        for (int it = 0; it < 16; ++it) {
            const int c = it * 8 + cg;
            tile[c][pl] = (p < NPIX) ? x[(size_t)(c0 + c) * NPIX + p] : 0.0f;
        }
        __syncthreads();
#pragma unroll
        for (int pass = 0; pass < 2; ++pass) {
            const int pix = pass * 16 + (tid >> 4);
            const int cb  = (tid & 15) * 8;
            if (p0 + pix < NPIX) {
                uint4 pk;
                pk.x = (unsigned int)f2bf(tile[cb + 0][pix]) | ((unsigned int)f2bf(tile[cb + 1][pix]) << 16);
                pk.y = (unsigned int)f2bf(tile[cb + 2][pix]) | ((unsigned int)f2bf(tile[cb + 3][pix]) << 16);
                pk.z = (unsigned int)f2bf(tile[cb + 4][pix]) | ((unsigned int)f2bf(tile[cb + 5][pix]) << 16);
                pk.w = (unsigned int)f2bf(tile[cb + 6][pix]) | ((unsigned int)f2bf(tile[cb + 7][pix]) << 16);
                *(uint4*)(xbT + (size_t)(p0 + pix) * IN_CH + c0 + cb) = pk;
            }
        }
    } else {
        // ---- prep_w part: row n = bin*82+t of Wr (4096,1024) ----
        const int row = bid - PXG;
        const int bin = row / COLB;
        const int t   = row - bin * COLB;
        const int c   = tid * 4;
        uint2 pk; pk.x = 0; pk.y = 0;
        if (bin < NBINS && t < NT) {
            const float4 v = *(const float4*)(conv_w + ((size_t)(t * NBINS + bin)) * IN_CH + c);
            pk.x = (unsigned int)f2bf(v.x) | ((unsigned int)f2bf(v.y) << 16);
            pk.y = (unsigned int)f2bf(v.z) | ((unsigned int)f2bf(v.w) << 16);
        }
        *(uint2*)(Wr + (size_t)row * IN_CH + c) = pk;
    }
}

// ---------- GEMM: sm[pix][4018] bf16 = xbT(10000,1024) @ Wr(4096,1024)^T ------------
// 128x128 tile, BK=64 (16 iters -> half the barrier drains), global_load_lds w=16,
// 4 waves (2x2), proven 16x16x32 fragment/epilogue mapping (row stride 32 -> 64).
__global__ __launch_bounds__(256) void gemm_sm(const ushortT* __restrict__ xbT,
                                               const ushortT* __restrict__ Wr,
                                               ushortT* __restrict__ sm) {
    __shared__ ushortT a_lds[128 * BK];   // 16 KB
    __shared__ ushortT b_lds[128 * BK];   // 16 KB
    const int tid  = threadIdx.x;
    const int lane = tid & 63;
    const int w    = tid >> 6;
    const int wm   = w & 1;
    const int wn   = w >> 1;
    const int n0   = blockIdx.x * 128;    // 0..31 tiles (mult of 8)
    const int p0   = blockIdx.y * 128;    // 0..78 tiles

    // staging: wave w covers rows w*32+i*8+(lane>>3), 16B at (lane&7)*8 elems;
    // 8 lanes x 16B = 128 B = one 64-ch row -> DMA lane*16 matches row-major layout.
    const int lr = lane >> 3;             // 0..7
    const int lc = (lane & 7) * 8;        // ch elem offset
    const ushortT* ag[4];
    const ushortT* bg[4];
    ushortT* al[4];
    ushortT* bl[4];
#pragma unroll
    for (int i = 0; i < 4; ++i) {
        int ap = p0 + w * 32 + i * 8 + lr; if (ap > NPIX - 1) ap = NPIX - 1;
        ag[i] = xbT + (size_t)ap * IN_CH + lc;
        bg[i] = Wr + (size_t)(n0 + w * 32 + i * 8 + lr) * IN_CH + lc;
        al[i] = a_lds + (w * 32 + i * 8) * BK;
        bl[i] = b_lds + (w * 32 + i * 8) * BK;
    }

    const int m_lane = lane & 15;
    const int k0     = (lane >> 4) * 8;

    f32x4 acc[4][4];
#pragma unroll
    for (int mt = 0; mt < 4; ++mt)
#pragma unroll
        for (int nt = 0; nt < 4; ++nt) acc[mt][nt] = (f32x4){0.f, 0.f, 0.f, 0.f};

    for (int kc = 0; kc < IN_CH / BK; ++kc) {
        __syncthreads();
#pragma unroll
        for (int i = 0; i < 4; ++i) {
            gld_lds16(ag[i], al[i]);
            gld_lds16(bg[i], bl[i]);
            ag[i] += BK; bg[i] += BK;
        }
        __syncthreads();

#pragma unroll
        for (int s = 0; s < 2; ++s) {
            const int ko = s * 32 + k0;
            bf16x8 af[4], bf[4];
#pragma unroll
            for (int mt = 0; mt < 4; ++mt)
                af[mt] = *(const bf16x8*)(a_lds + (wm * 64 + mt * 16 + m_lane) * BK + ko);
#pragma unroll
            for (int nt = 0; nt < 4; ++nt)
                bf[nt] = *(const bf16x8*)(b_lds + (wn * 64 + nt * 16 + m_lane) * BK + ko);
#pragma unroll
            for (int mt = 0; mt < 4; ++mt)
#pragma unroll
                for (int nt = 0; nt < 4; ++nt)
                    acc[mt][nt] = __builtin_amdgcn_mfma_f32_16x16x32_bf16(af[mt], bf[nt], acc[mt][nt], 0, 0, 0);
        }
    }

    const int prow_base = p0 + wm * 64 + (lane >> 4) * 4;
    const int ncol_base = n0 + wn * 64 + m_lane;
#pragma unroll
    for (int mt = 0; mt < 4; ++mt) {
#pragma unroll
        for (int rg = 0; rg < 4; ++rg) {
            const int p = prow_base + mt * 16 + rg;
            if (p < NPIX) {
                ushortT* rowp = sm + (size_t)p * SROW;
#pragma unroll
                for (int nt = 0; nt < 4; ++nt) {
                    const int n = ncol_base + nt * 16;
                    if (n < NCOL) rowp[n] = f2bf(acc[mt][nt][rg]);
                }
            }
        }
    }
}

// ---------- pooling: grid (region, 8 groups); 12 streams x 9-deep register prefetch -
__global__ __launch_bounds__(256) void pool_kernel(const ushortT* __restrict__ sm,
                                                   const float* __restrict__ regions,
                                                   const float* __restrict__ conv_b,
                                                   float* __restrict__ out) {
    __shared__ int   rowo[28]; __shared__ float roww[28];
    __shared__ int   coli[28]; __shared__ float colw[28];
    __shared__ int   pofs[108];
    __shared__ float pw[108];
    __shared__ float part[12][84];
    const int tid = threadIdx.x;
    const int r = blockIdx.x;
    const int g = blockIdx.y;   // 0..7

    if (tid < 28) {
        const float4 reg = *(const float4*)(regions + (size_t)r * 4);
        const float top = (reg.x - reg.z * 0.5f) * (float)HH;
        const float bh  = reg.z * ((float)HH / (float)KGRID);
        const int u = tid >> 2, i = tid & 3;
        const int s = i >> 1, hi = i & 1;
        float y = top + ((float)u + ((float)s + 0.5f) * 0.5f) * bh;
        y = fminf(fmaxf(y, 0.0f), (float)(HH - 1));
        const float y0f = floorf(y);
        const int y0 = (int)y0f;
        const float wy1 = y - y0f;
        rowo[tid] = (hi ? min(y0 + 1, HH - 1) : y0) * WW;
        roww[tid] = hi ? wy1 : (1.0f - wy1);
    } else if (tid >= 32 && tid < 60) {
        const float4 reg = *(const float4*)(regions + (size_t)r * 4);
        const float left = (reg.y - reg.w * 0.5f) * (float)WW;
        const float bw   = reg.w * ((float)WW / (float)KGRID);
        const int idx = tid - 32;
        const int v = idx >> 2, j = idx & 3;
        const int s = j >> 1, hi = j & 1;
        float xx = left + ((float)v + ((float)s + 0.5f) * 0.5f) * bw;
        xx = fminf(fmaxf(xx, 0.0f), (float)(WW - 1));
        const float x0f = floorf(xx);
        const int x0 = (int)x0f;
        const float wx1 = xx - x0f;
        coli[idx] = hi ? min(x0 + 1, WW - 1) : x0;
        colw[idx] = hi ? wx1 : (1.0f - wx1);
    }
    __syncthreads();
    if (tid < 108) {
        if (tid < 98) {                     // 8*98 == 784 exactly
            const int tt = g * 98 + tid;
            const int bin = tt >> 4, tap = tt & 15;
            const int u = bin / KGRID, v = bin - u * KGRID;
            const int i = tap >> 2, j = tap & 3;
            const int pix = rowo[u * 4 + i] + coli[v * 4 + j];
            pofs[tid] = pix * SROW + bin * COLB;
            pw[tid]   = roww[u * 4 + i] * colw[v * 4 + j] * (1.0f / 196.0f);
        } else {                            // padding: read sm[0..], weight 0
            pofs[tid] = 0;
            pw[tid]   = 0.0f;
        }
    }
    __syncthreads();

    const int lane = tid & 63, w = tid >> 6;
    const int sub  = lane / 21;             // 0..2 active, lane 63 idle
    const int cidx = lane - sub * 21;       // 0..20 -> channels cidx*4..+3
    if (sub < 3) {
        const int str = w * 3 + sub;        // 0..11
        const int l2  = cidx * 4;
        uint2 v[9];
#pragma unroll
        for (int it = 0; it < 9; ++it)
            v[it] = *(const uint2*)(sm + pofs[str * 9 + it] + l2);
        float a0 = 0.f, a1 = 0.f, a2 = 0.f, a3 = 0.f;
#pragma unroll
        for (int it = 0; it < 9; ++it) {
            const float wt = pw[str * 9 + it];
            a0 += wt * bf_lo(v[it].x); a1 += wt * bf_hi(v[it].x);
            a2 += wt * bf_lo(v[it].y); a3 += wt * bf_hi(v[it].y);
        }
        float4 p4; p4.x = a0; p4.y = a1; p4.z = a2; p4.w = a3;
        *(float4*)&part[str][l2] = p4;
    }
    __syncthreads();
    if (tid < NT) {
        float v = 0.f;
#pragma unroll
        for (int s = 0; s < 12; ++s) v += part[s][tid];
        if (g == 0) {
            float bsum = 0.f;
            for (int bin = 0; bin < NBINS; ++bin) bsum += conv_b[tid * NBINS + bin];
            v += bsum * (1.0f / (float)NBINS);
        }
        atomicAdd(out + (size_t)r * NT + tid, v);
    }
}

// =======================  fallback path (round-1 kernel)  ==========================
__global__ __launch_bounds__(256) void xpose_kernel(const float* __restrict__ x,
                                                    float* __restrict__ xt) {
    __shared__ float tile[32][33];
    const int p0 = blockIdx.x * 32;
    const int c0 = blockIdx.y * 32;
    const int tx = threadIdx.x;
    const int ty = threadIdx.y;
#pragma unroll
    for (int k = 0; k < 32; k += 8) {
        const int p = p0 + tx;
        if (p < NPIX) tile[ty + k][tx] = x[(size_t)(c0 + ty + k) * NPIX + p];
    }
    __syncthreads();
#pragma unroll
    for (int k = 0; k < 32; k += 8) {
        const int p = p0 + ty + k;
        if (p < NPIX) xt[(size_t)p * IN_CH + (c0 + tx)] = tile[tx][ty + k];
    }
}

template <bool XPOSED>
__global__ __launch_bounds__(256) void psroi_kernel(
    const float* __restrict__ xsrc, const float* __restrict__ regions,
    const float* __restrict__ conv_w, const float* __restrict__ conv_b,
    float* __restrict__ out) {
    __shared__ float w_lds[32 * 96];
    __shared__ float g_lds[32 * 64];
    __shared__ int   rowoff[64][4];
    __shared__ float rowwf[64][4];
    __shared__ int   colidx[64][4];
    __shared__ float colwf[64][4];
    const int tid = threadIdx.x;
    const int bin = blockIdx.x >> 4;
    const int rg  = blockIdx.x & 15;
    const int u = bin / KGRID, v = bin % KGRID;
    const int r0 = rg * 64;
    if (tid < 64) {
        const float4 reg = *(const float4*)(regions + (size_t)(r0 + tid) * 4);
        const float top  = (reg.x - reg.z * 0.5f) * (float)HH;
        const float left = (reg.y - reg.w * 0.5f) * (float)WW;
        const float bh = reg.z * ((float)HH / (float)KGRID);
        const float bw = reg.w * ((float)WW / (float)KGRID);
        const float scale = 1.0f / 196.0f;
#pragma unroll
        for (int s = 0; s < 2; s++) {
            const float off = (s + 0.5f) * 0.5f;
            float yy = top + ((float)u + off) * bh;
            yy = fminf(fmaxf(yy, 0.0f), (float)(HH - 1));
            const float y0f = floorf(yy);
            const int y0 = (int)y0f;
            const float wy1 = yy - y0f;
            rowoff[tid][2 * s] = y0 * WW;
            rowoff[tid][2 * s + 1] = min(y0 + 1, HH - 1) * WW;
            rowwf[tid][2 * s] = (1.0f - wy1) * scale;
            rowwf[tid][2 * s + 1] = wy1 * scale;
            float xx = left + ((float)v + off) * bw;
            xx = fminf(fmaxf(xx, 0.0f), (float)(WW - 1));
            const float x0f = floorf(xx);
            const int x0 = (int)x0f;
            const float wx1 = xx - x0f;
            colidx[tid][2 * s] = x0;
            colidx[tid][2 * s + 1] = min(x0 + 1, WW - 1);
            colwf[tid][2 * s] = 1.0f - wx1;
            colwf[tid][2 * s + 1] = wx1;
        }
    }
    const int ri = tid & 15, tq = tid >> 4, rb = tid >> 2, cq = tid & 3;
    float acc[4][6];
#pragma unroll
    for (int m = 0; m < 4; m++)
#pragma unroll
        for (int k = 0; k < 6; k++) acc[m][k] = 0.0f;
    for (int chunk = 0; chunk < IN_CH / 32; chunk++) {
        const int c0 = chunk * 32;
        __syncthreads();
#pragma unroll
        for (int it = 0; it < 12; it++) {
            const int idx = it * 256 + tid;
            const int t = idx >> 5, c = idx & 31;
            float val = 0.0f;
            if (t < NT) val = conv_w[(size_t)(t * NBINS + bin) * IN_CH + c0 + c];
            w_lds[c * 96 + t] = val;
        }
        const int cbase = c0 + cq * 8;
        float g8[8];
#pragma unroll
        for (int cc = 0; cc < 8; cc++) g8[cc] = 0.0f;
#pragma unroll
        for (int i = 0; i < 4; i++) {
            const int ro = rowoff[rb][i];
            const float wy = rowwf[rb][i];
#pragma unroll
            for (int j = 0; j < 4; j++) {
                const int pix = ro + colidx[rb][j];
                const float wv = wy * colwf[rb][j];
                if (XPOSED) {
                    const float4* p = (const float4*)(xsrc + (size_t)pix * IN_CH + cbase);
                    const float4 a = p[0]; const float4 b = p[1];
                    g8[0] += wv * a.x; g8[1] += wv * a.y; g8[2] += wv * a.z; g8[3] += wv * a.w;
                    g8[4] += wv * b.x; g8[5] += wv * b.y; g8[6] += wv * b.z; g8[7] += wv * b.w;
                } else {
#pragma unroll
                    for (int cc = 0; cc < 8; cc++)
                        g8[cc] += wv * xsrc[(size_t)(cbase + cc) * NPIX + pix];
                }
            }
        }
#pragma unroll
        for (int cc = 0; cc < 8; cc++) g_lds[(cq * 8 + cc) * 64 + rb] = g8[cc];
        __syncthreads();
#pragma unroll 4
        for (int c = 0; c < 32; c++) {
            float wv[6];
#pragma unroll
            for (int k = 0; k < 6; k++) wv[k] = w_lds[c * 96 + tq * 6 + k];
            const float4 gq = *(const float4*)&g_lds[c * 64 + ri * 4];
            const float gm[4] = {gq.x, gq.y, gq.z, gq.w};
#pragma unroll
            for (int m = 0; m < 4; m++)
#pragma unroll
                for (int k = 0; k < 6; k++) acc[m][k] += gm[m] * wv[k];
        }
    }
    const float invK2 = 1.0f / 49.0f;
#pragma unroll
    for (int k = 0; k < 6; k++) {
        const int t = tq * 6 + k;
        if (t < NT) {
            const float bterm = conv_b[t * NBINS + bin] * invK2;
#pragma unroll
            for (int m = 0; m < 4; m++) {
                const int rr = r0 + ri * 4 + m;
                atomicAdd(&out[(size_t)rr * NT + t], acc[m][k] + bterm);
            }
        }
    }
}

extern "C" void kernel_launch(void* const* d_in, const int* in_sizes, int n_in,
                              void* d_out, int out_size, void* d_ws, size_t ws_size,
                              hipStream_t stream) {
    const float* x       = (const float*)d_in[0];
    const float* regions = (const float*)d_in[1];
    const float* conv_w  = (const float*)d_in[2];
    const float* conv_b  = (const float*)d_in[3];
    float* out = (float*)d_out;

    const size_t sz_xbT = (size_t)NPIX * IN_CH * 2;          // 20,480,000
    const size_t sz_Wr  = (size_t)NPADW * IN_CH * 2;         //  8,388,608
    const size_t sz_sm  = (size_t)NPIX * SROW * 2 + 256;     // 80,360,000 + slack
    const size_t need   = sz_xbT + sz_Wr + sz_sm;            // ~109.2 MB

    if (ws_size >= need) {
        ushortT* xbT = (ushortT*)d_ws;
        ushortT* Wr  = (ushortT*)((char*)d_ws + sz_xbT);
        ushortT* sm  = (ushortT*)((char*)d_ws + sz_xbT + sz_Wr);
        hipMemsetAsync(out, 0, (size_t)out_size * sizeof(float), stream);
        prep_fused<<<dim3(PREPG), 256, 0, stream>>>(x, xbT, conv_w, Wr);
        gemm_sm<<<dim3(NPADW / 128, (NPIX + 127) / 128), 256, 0, stream>>>(xbT, Wr, sm);
        pool_kernel<<<dim3(NREG, NG), 256, 0, stream>>>(sm, regions, conv_b, out);
    } else {
        hipMemsetAsync(out, 0, (size_t)out_size * sizeof(float), stream);
        const size_t xt_bytes = (size_t)NPIX * IN_CH * sizeof(float);
        const dim3 mainGrid(NBINS * 16);
        if (ws_size >= xt_bytes) {
            float* xt = (float*)d_ws;
            xpose_kernel<<<dim3((NPIX + 31) / 32, IN_CH / 32), dim3(32, 8), 0, stream>>>(x, xt);
            psroi_kernel<true><<<mainGrid, 256, 0, stream>>>(xt, regions, conv_w, conv_b, out);
        } else {
            psroi_kernel<false><<<mainGrid, 256, 0, stream>>>(x, regions, conv_w, conv_b, out);
        }
    }
}

// Round 11
// 237.773 us; speedup vs baseline: 1.0839x; 1.0839x over previous
//
#include <hip/hip_runtime.h>
#include <cstddef>

#define IN_CH 1024
#define NT    81
#define KGRID 7
#define NBINS 49
#define HH    100
#define WW    100
#define NPIX  (HH*WW)
#define NREG  1024
#define COLB  82            // gemm column group per bin: 81 real + 1 zero pad
#define NCOL  (NBINS*COLB)  // 4018 gemm columns (32 N-tiles of 128)
#define NPADW 4096          // 32 N-tiles (multiple of 8 XCDs)
#define SBIN  84            // sm per-bin stride in BYTES (int8), 4-aligned rows
#define SROWB (NBINS*SBIN)  // 4116 B per pixel row
#define NG    8             // pool tap-groups per region (8*98 = 784)
#define NPT   79            // pix tiles
#define NSC   2560          // scale table floats (79*32 = 2528 used, padded)
#define PXB   ((NPIX + 31) / 32)        // 313 prep_x col-blocks
#define PXG   (PXB * (IN_CH / 128))     // 2504 prep_x blocks
#define PREPG (PXG + NPADW)             // + 4096 prep_w blocks

typedef unsigned short ushortT;
typedef short bf16x8 __attribute__((ext_vector_type(8)));
typedef float f32x4  __attribute__((ext_vector_type(4)));

static __device__ __forceinline__ unsigned short f2bf(float f) {
    unsigned int u = __builtin_bit_cast(unsigned int, f);
    return (unsigned short)((u + 0x7fffu + ((u >> 16) & 1u)) >> 16);
}

// async global->LDS, 16B per lane; LDS dest = wave-uniform base + lane*16
static __device__ __forceinline__ void gld_lds16(const ushortT* g, ushortT* l) {
    __builtin_amdgcn_global_load_lds(
        (__attribute__((address_space(1))) void*)(unsigned long long)(uintptr_t)g,
        (__attribute__((address_space(3))) void*)(unsigned int)(unsigned long long)(uintptr_t)l,
        16, 0, 0);
}

// ---------- fused prep: x (C,P) fp32 -> xbT (P,C) bf16  |  conv_w -> Wr -------------
__global__ __launch_bounds__(256) void prep_fused(const float* __restrict__ x,
                                                  ushortT* __restrict__ xbT,
                                                  const float* __restrict__ conv_w,
                                                  ushortT* __restrict__ Wr) {
    __shared__ float tile[128][33];
    const int tid = threadIdx.x;
    const int bid = blockIdx.x;
    if (bid < PXG) {
        const int p0 = (bid % PXB) * 32;
        const int c0 = (bid / PXB) * 128;
        const int pl = tid & 31;
        const int cg = tid >> 5;          // 0..7
        const int p = p0 + pl;
#pragma unroll
        for (int it = 0; it < 16; ++it) {
            const int c = it * 8 + cg;
            tile[c][pl] = (p < NPIX) ? x[(size_t)(c0 + c) * NPIX + p] : 0.0f;
        }
        __syncthreads();
#pragma unroll
        for (int pass = 0; pass < 2; ++pass) {
            const int pix = pass * 16 + (tid >> 4);
            const int cb  = (tid & 15) * 8;
            if (p0 + pix < NPIX) {
                uint4 pk;
                pk.x = (unsigned int)f2bf(tile[cb + 0][pix]) | ((unsigned int)f2bf(tile[cb + 1][pix]) << 16);
                pk.y = (unsigned int)f2bf(tile[cb + 2][pix]) | ((unsigned int)f2bf(tile[cb + 3][pix]) << 16);
                pk.z = (unsigned int)f2bf(tile[cb + 4][pix]) | ((unsigned int)f2bf(tile[cb + 5][pix]) << 16);
                pk.w = (unsigned int)f2bf(tile[cb + 6][pix]) | ((unsigned int)f2bf(tile[cb + 7][pix]) << 16);
                *(uint4*)(xbT + (size_t)(p0 + pix) * IN_CH + c0 + cb) = pk;
            }
        }
    } else {
        const int row = bid - PXG;
        const int bin = row / COLB;
        const int t   = row - bin * COLB;
        const int c   = tid * 4;
        uint2 pk; pk.x = 0; pk.y = 0;
        if (bin < NBINS && t < NT) {
            const float4 v = *(const float4*)(conv_w + ((size_t)(t * NBINS + bin)) * IN_CH + c);
            pk.x = (unsigned int)f2bf(v.x) | ((unsigned int)f2bf(v.y) << 16);
            pk.y = (unsigned int)f2bf(v.z) | ((unsigned int)f2bf(v.w) << 16);
        }
        *(uint2*)(Wr + (size_t)row * IN_CH + c) = pk;
    }
}

// ---------- GEMM: sm int8[pix][bin*84+t] x scales[pt*32+nt] ------------------------
// Round-8 proven structure: 128x128 tile, BK=32, global_load_lds w=16, 4 waves (2x2).
// Epilogue: block amax (LDS tree over reused a_lds) -> dynamic int8 quantization.
__global__ __launch_bounds__(256) void gemm_sm(const ushortT* __restrict__ xbT,
                                               const ushortT* __restrict__ Wr,
                                               unsigned char* __restrict__ sm,
                                               float* __restrict__ scales) {
    __shared__ ushortT a_lds[128 * 32];
    __shared__ ushortT b_lds[128 * 32];
    const int tid  = threadIdx.x;
    const int lane = tid & 63;
    const int w    = tid >> 6;
    const int wm   = w & 1;
    const int wn   = w >> 1;
    const int n0   = blockIdx.x * 128;    // nt = blockIdx.x (0..31, mult of 8)
    const int p0   = blockIdx.y * 128;    // pt = blockIdx.y (0..78)

    const int srow0 = w * 32 + (lane >> 2);
    const int scol  = (lane & 3) * 8;
    int ap0 = p0 + srow0;      if (ap0 > NPIX - 1) ap0 = NPIX - 1;
    int ap1 = p0 + srow0 + 16; if (ap1 > NPIX - 1) ap1 = NPIX - 1;
    const ushortT* ag0 = xbT + (size_t)ap0 * IN_CH + scol;
    const ushortT* ag1 = xbT + (size_t)ap1 * IN_CH + scol;
    const ushortT* bg0 = Wr + (size_t)(n0 + srow0) * IN_CH + scol;
    const ushortT* bg1 = Wr + (size_t)(n0 + srow0 + 16) * IN_CH + scol;
    ushortT* al0 = a_lds + (w * 32) * 32;
    ushortT* al1 = a_lds + (w * 32 + 16) * 32;
    ushortT* bl0 = b_lds + (w * 32) * 32;
    ushortT* bl1 = b_lds + (w * 32 + 16) * 32;

    const int m_lane = lane & 15;
    const int k0     = (lane >> 4) * 8;

    f32x4 acc[4][4];
#pragma unroll
    for (int mt = 0; mt < 4; ++mt)
#pragma unroll
        for (int nt = 0; nt < 4; ++nt) acc[mt][nt] = (f32x4){0.f, 0.f, 0.f, 0.f};

    for (int kc = 0; kc < IN_CH / 32; ++kc) {
        __syncthreads();
        gld_lds16(ag0, al0);
        gld_lds16(ag1, al1);
        gld_lds16(bg0, bl0);
        gld_lds16(bg1, bl1);
        ag0 += 32; ag1 += 32; bg0 += 32; bg1 += 32;
        __syncthreads();

        bf16x8 af[4], bf[4];
#pragma unroll
        for (int mt = 0; mt < 4; ++mt)
            af[mt] = *(const bf16x8*)(a_lds + (wm * 64 + mt * 16 + m_lane) * 32 + k0);
#pragma unroll
        for (int nt = 0; nt < 4; ++nt)
            bf[nt] = *(const bf16x8*)(b_lds + (wn * 64 + nt * 16 + m_lane) * 32 + k0);
#pragma unroll
        for (int mt = 0; mt < 4; ++mt)
#pragma unroll
            for (int nt = 0; nt < 4; ++nt)
                acc[mt][nt] = __builtin_amdgcn_mfma_f32_16x16x32_bf16(af[mt], bf[nt], acc[mt][nt], 0, 0, 0);
    }

    // ---- block amax reduction (reuse a_lds as float scratch) ----
    float am = 0.0f;
#pragma unroll
    for (int mt = 0; mt < 4; ++mt)
#pragma unroll
        for (int nt = 0; nt < 4; ++nt)
#pragma unroll
            for (int rg = 0; rg < 4; ++rg)
                am = fmaxf(am, fabsf(acc[mt][nt][rg]));
    __syncthreads();                      // all frag reads done before LDS reuse
    float* red = (float*)a_lds;
    red[tid] = am;
    __syncthreads();
#pragma unroll
    for (int s = 128; s > 0; s >>= 1) {
        if (tid < s) red[tid] = fmaxf(red[tid], red[tid + s]);
        __syncthreads();
    }
    const float amax = fmaxf(red[0], 1e-30f);
    const float inv  = 127.0f / amax;
    if (tid == 0) scales[blockIdx.y * 32 + blockIdx.x] = amax * (1.0f / 127.0f);

    // ---- quantize + store: n = bin*82+t -> byte offset n + 2*(n/82) ----
    const int prow_base = p0 + wm * 64 + (lane >> 4) * 4;
    const int ncol_base = n0 + wn * 64 + m_lane;
    int  coloff[4];
    bool cok[4];
#pragma unroll
    for (int nt = 0; nt < 4; ++nt) {
        const int n = ncol_base + nt * 16;
        cok[nt] = (n < NCOL);
        coloff[nt] = n + 2 * (n / COLB);
    }
#pragma unroll
    for (int mt = 0; mt < 4; ++mt) {
#pragma unroll
        for (int rg = 0; rg < 4; ++rg) {
            const int p = prow_base + mt * 16 + rg;
            if (p < NPIX) {
                unsigned char* rowp = sm + (size_t)p * SROWB;
#pragma unroll
                for (int nt = 0; nt < 4; ++nt)
                    if (cok[nt]) {
                        const int q = __float2int_rn(acc[mt][nt][rg] * inv);
                        rowp[coloff[nt]] = (unsigned char)(signed char)q;
                    }
            }
        }
    }
}

// ---------- pooling: grid (region, 8 groups); 12 streams x 9-deep register prefetch -
// int8 sm: tap row = 84 B; 21 lanes x uint (4 ch); decode q * (wt * scale[pt,nt]).
__global__ __launch_bounds__(256) void pool_kernel(const unsigned char* __restrict__ sm,
                                                   const float* __restrict__ scales,
                                                   const float* __restrict__ regions,
                                                   const float* __restrict__ conv_b,
                                                   float* __restrict__ out) {
    __shared__ int   rowo[28]; __shared__ float roww[28];
    __shared__ int   coli[28]; __shared__ float colw[28];
    __shared__ int   pofs[108];
    __shared__ float pw[108];
    __shared__ int   pptb[108];   // (pix>>7)*32
    __shared__ int   pnb[108];    // bin*82
    __shared__ float part[12][84];
    const int tid = threadIdx.x;
    const int r = blockIdx.x;
    const int g = blockIdx.y;   // 0..7

    if (tid < 28) {
        const float4 reg = *(const float4*)(regions + (size_t)r * 4);
        const float top = (reg.x - reg.z * 0.5f) * (float)HH;
        const float bh  = reg.z * ((float)HH / (float)KGRID);
        const int u = tid >> 2, i = tid & 3;
        const int s = i >> 1, hi = i & 1;
        float y = top + ((float)u + ((float)s + 0.5f) * 0.5f) * bh;
        y = fminf(fmaxf(y, 0.0f), (float)(HH - 1));
        const float y0f = floorf(y);
        const int y0 = (int)y0f;
        const float wy1 = y - y0f;
        rowo[tid] = (hi ? min(y0 + 1, HH - 1) : y0) * WW;
        roww[tid] = hi ? wy1 : (1.0f - wy1);
    } else if (tid >= 32 && tid < 60) {
        const float4 reg = *(const float4*)(regions + (size_t)r * 4);
        const float left = (reg.y - reg.w * 0.5f) * (float)WW;
        const float bw   = reg.w * ((float)WW / (float)KGRID);
        const int idx = tid - 32;
        const int v = idx >> 2, j = idx & 3;
        const int s = j >> 1, hi = j & 1;
        float xx = left + ((float)v + ((float)s + 0.5f) * 0.5f) * bw;
        xx = fminf(fmaxf(xx, 0.0f), (float)(WW - 1));
        const float x0f = floorf(xx);
        const int x0 = (int)x0f;
        const float wx1 = xx - x0f;
        coli[idx] = hi ? min(x0 + 1, WW - 1) : x0;
        colw[idx] = hi ? wx1 : (1.0f - wx1);
    }
    __syncthreads();
    if (tid < 108) {
        if (tid < 98) {                     // 8*98 == 784 exactly
            const int tt = g * 98 + tid;
            const int bin = tt >> 4, tap = tt & 15;
            const int u = bin / KGRID, v = bin - u * KGRID;
            const int i = tap >> 2, j = tap & 3;
            const int pix = rowo[u * 4 + i] + coli[v * 4 + j];
            pofs[tid] = pix * SROWB + bin * SBIN;     // BYTE offset, 4-aligned
            pw[tid]   = roww[u * 4 + i] * colw[v * 4 + j] * (1.0f / 196.0f);
            pptb[tid] = (pix >> 7) * 32;
            pnb[tid]  = bin * COLB;
        } else {
            pofs[tid] = 0;
            pw[tid]   = 0.0f;
            pptb[tid] = 0;
            pnb[tid]  = 0;
        }
    }
    __syncthreads();

    const int lane = tid & 63, w = tid >> 6;
    const int sub  = lane / 21;             // 0..2 active, lane 63 idle
    const int cidx = lane - sub * 21;       // 0..20 -> channels cidx*4..+3
    if (sub < 3) {
        const int str = w * 3 + sub;        // 0..11
        const int l4  = cidx * 4;
        unsigned int v[9];
#pragma unroll
        for (int it = 0; it < 9; ++it)
            v[it] = *(const unsigned int*)(sm + pofs[str * 9 + it] + l4);
        float a0 = 0.f, a1 = 0.f, a2 = 0.f, a3 = 0.f;
#pragma unroll
        for (int it = 0; it < 9; ++it) {
            const int lt = str * 9 + it;
            const int nb  = pnb[lt] + l4;       // n of channel 0
            const int nt0 = nb >> 7;
            const int rr  = nb & 127;
            const float s0 = scales[pptb[lt] + nt0];
            const float s1 = scales[pptb[lt] + nt0 + 1];
            const float wt = pw[lt];
            const float w0 = wt * s0, w1 = wt * s1;
            const int q0 = (int)(signed char)(v[it] & 0xff);
            const int q1 = (int)(signed char)((v[it] >> 8) & 0xff);
            const int q2 = (int)(signed char)((v[it] >> 16) & 0xff);
            const int q3 = (int)(signed char)(v[it] >> 24);
            a0 += ((rr < 128) ? w0 : w1) * (float)q0;
            a1 += ((rr < 127) ? w0 : w1) * (float)q1;
            a2 += ((rr < 126) ? w0 : w1) * (float)q2;
            a3 += ((rr < 125) ? w0 : w1) * (float)q3;
        }
        float4 p4; p4.x = a0; p4.y = a1; p4.z = a2; p4.w = a3;
        *(float4*)&part[str][l4] = p4;
    }
    __syncthreads();
    if (tid < NT) {
        float v = 0.f;
#pragma unroll
        for (int s = 0; s < 12; ++s) v += part[s][tid];
        if (g == 0) {
            float bsum = 0.f;
            for (int bin = 0; bin < NBINS; ++bin) bsum += conv_b[tid * NBINS + bin];
            v += bsum * (1.0f / (float)NBINS);
        }
        atomicAdd(out + (size_t)r * NT + tid, v);
    }
}

// =======================  fallback path (round-1 kernel)  ==========================
__global__ __launch_bounds__(256) void xpose_kernel(const float* __restrict__ x,
                                                    float* __restrict__ xt) {
    __shared__ float tile[32][33];
    const int p0 = blockIdx.x * 32;
    const int c0 = blockIdx.y * 32;
    const int tx = threadIdx.x;
    const int ty = threadIdx.y;
#pragma unroll
    for (int k = 0; k < 32; k += 8) {
        const int p = p0 + tx;
        if (p < NPIX) tile[ty + k][tx] = x[(size_t)(c0 + ty + k) * NPIX + p];
    }
    __syncthreads();
#pragma unroll
    for (int k = 0; k < 32; k += 8) {
        const int p = p0 + ty + k;
        if (p < NPIX) xt[(size_t)p * IN_CH + (c0 + tx)] = tile[tx][ty + k];
    }
}

template <bool XPOSED>
__global__ __launch_bounds__(256) void psroi_kernel(
    const float* __restrict__ xsrc, const float* __restrict__ regions,
    const float* __restrict__ conv_w, const float* __restrict__ conv_b,
    float* __restrict__ out) {
    __shared__ float w_lds[32 * 96];
    __shared__ float g_lds[32 * 64];
    __shared__ int   rowoff[64][4];
    __shared__ float rowwf[64][4];
    __shared__ int   colidx[64][4];
    __shared__ float colwf[64][4];
    const int tid = threadIdx.x;
    const int bin = blockIdx.x >> 4;
    const int rg  = blockIdx.x & 15;
    const int u = bin / KGRID, v = bin % KGRID;
    const int r0 = rg * 64;
    if (tid < 64) {
        const float4 reg = *(const float4*)(regions + (size_t)(r0 + tid) * 4);
        const float top  = (reg.x - reg.z * 0.5f) * (float)HH;
        const float left = (reg.y - reg.w * 0.5f) * (float)WW;
        const float bh = reg.z * ((float)HH / (float)KGRID);
        const float bw = reg.w * ((float)WW / (float)KGRID);
        const float scale = 1.0f / 196.0f;
#pragma unroll
        for (int s = 0; s < 2; s++) {
            const float off = (s + 0.5f) * 0.5f;
            float yy = top + ((float)u + off) * bh;
            yy = fminf(fmaxf(yy, 0.0f), (float)(HH - 1));
            const float y0f = floorf(yy);
            const int y0 = (int)y0f;
            const float wy1 = yy - y0f;
            rowoff[tid][2 * s] = y0 * WW;
            rowoff[tid][2 * s + 1] = min(y0 + 1, HH - 1) * WW;
            rowwf[tid][2 * s] = (1.0f - wy1) * scale;
            rowwf[tid][2 * s + 1] = wy1 * scale;
            float xx = left + ((float)v + off) * bw;
            xx = fminf(fmaxf(xx, 0.0f), (float)(WW - 1));
            const float x0f = floorf(xx);
            const int x0 = (int)x0f;
            const float wx1 = xx - x0f;
            colidx[tid][2 * s] = x0;
            colidx[tid][2 * s + 1] = min(x0 + 1, WW - 1);
            colwf[tid][2 * s] = 1.0f - wx1;
            colwf[tid][2 * s + 1] = wx1;
        }
    }
    const int ri = tid & 15, tq = tid >> 4, rb = tid >> 2, cq = tid & 3;
    float acc[4][6];
#pragma unroll
    for (int m = 0; m < 4; m++)
#pragma unroll
        for (int k = 0; k < 6; k++) acc[m][k] = 0.0f;
    for (int chunk = 0; chunk < IN_CH / 32; chunk++) {
        const int c0 = chunk * 32;
        __syncthreads();
#pragma unroll
        for (int it = 0; it < 12; it++) {
            const int idx = it * 256 + tid;
            const int t = idx >> 5, c = idx & 31;
            float val = 0.0f;
            if (t < NT) val = conv_w[(size_t)(t * NBINS + bin) * IN_CH + c0 + c];
            w_lds[c * 96 + t] = val;
        }
        const int cbase = c0 + cq * 8;
        float g8[8];
#pragma unroll
        for (int cc = 0; cc < 8; cc++) g8[cc] = 0.0f;
#pragma unroll
        for (int i = 0; i < 4; i++) {
            const int ro = rowoff[rb][i];
            const float wy = rowwf[rb][i];
#pragma unroll
            for (int j = 0; j < 4; j++) {
                const int pix = ro + colidx[rb][j];
                const float wv = wy * colwf[rb][j];
                if (XPOSED) {
                    const float4* p = (const float4*)(xsrc + (size_t)pix * IN_CH + cbase);
                    const float4 a = p[0]; const float4 b = p[1];
                    g8[0] += wv * a.x; g8[1] += wv * a.y; g8[2] += wv * a.z; g8[3] += wv * a.w;
                    g8[4] += wv * b.x; g8[5] += wv * b.y; g8[6] += wv * b.z; g8[7] += wv * b.w;
                } else {
#pragma unroll
                    for (int cc = 0; cc < 8; cc++)
                        g8[cc] += wv * xsrc[(size_t)(cbase + cc) * NPIX + pix];
                }
            }
        }
#pragma unroll
        for (int cc = 0; cc < 8; cc++) g_lds[(cq * 8 + cc) * 64 + rb] = g8[cc];
        __syncthreads();
#pragma unroll 4
        for (int c = 0; c < 32; c++) {
            float wv[6];
#pragma unroll
            for (int k = 0; k < 6; k++) wv[k] = w_lds[c * 96 + tq * 6 + k];
            const float4 gq = *(const float4*)&g_lds[c * 64 + ri * 4];
            const float gm[4] = {gq.x, gq.y, gq.z, gq.w};
#pragma unroll
            for (int m = 0; m < 4; m++)
#pragma unroll
                for (int k = 0; k < 6; k++) acc[m][k] += gm[m] * wv[k];
        }
    }
    const float invK2 = 1.0f / 49.0f;
#pragma unroll
    for (int k = 0; k < 6; k++) {
        const int t = tq * 6 + k;
        if (t < NT) {
            const float bterm = conv_b[t * NBINS + bin] * invK2;
#pragma unroll
            for (int m = 0; m < 4; m++) {
                const int rr = r0 + ri * 4 + m;
                atomicAdd(&out[(size_t)rr * NT + t], acc[m][k] + bterm);
            }
        }
    }
}

extern "C" void kernel_launch(void* const* d_in, const int* in_sizes, int n_in,
                              void* d_out, int out_size, void* d_ws, size_t ws_size,
                              hipStream_t stream) {
    const float* x       = (const float*)d_in[0];
    const float* regions = (const float*)d_in[1];
    const float* conv_w  = (const float*)d_in[2];
    const float* conv_b  = (const float*)d_in[3];
    float* out = (float*)d_out;

    const size_t sz_xbT = (size_t)NPIX * IN_CH * 2;          // 20,480,000
    const size_t sz_Wr  = (size_t)NPADW * IN_CH * 2;         //  8,388,608
    const size_t sz_sm  = (size_t)NPIX * SROWB + 256;        // 41,160,000 + slack
    const size_t sz_sc  = (size_t)NSC * sizeof(float);       // 10,240
    const size_t need   = sz_xbT + sz_Wr + sz_sm + sz_sc;    // ~70.0 MB

    if (ws_size >= need) {
        ushortT* xbT = (ushortT*)d_ws;
        ushortT* Wr  = (ushortT*)((char*)d_ws + sz_xbT);
        unsigned char* sm = (unsigned char*)d_ws + sz_xbT + sz_Wr;
        float* scales = (float*)((char*)d_ws + sz_xbT + sz_Wr + sz_sm);
        hipMemsetAsync(out, 0, (size_t)out_size * sizeof(float), stream);
        prep_fused<<<dim3(PREPG), 256, 0, stream>>>(x, xbT, conv_w, Wr);
        gemm_sm<<<dim3(NPADW / 128, (NPIX + 127) / 128), 256, 0, stream>>>(xbT, Wr, sm, scales);
        pool_kernel<<<dim3(NREG, NG), 256, 0, stream>>>(sm, scales, regions, conv_b, out);
    } else {
        hipMemsetAsync(out, 0, (size_t)out_size * sizeof(float), stream);
        const size_t xt_bytes = (size_t)NPIX * IN_CH * sizeof(float);
        const dim3 mainGrid(NBINS * 16);
        if (ws_size >= xt_bytes) {
            float* xt = (float*)d_ws;
            xpose_kernel<<<dim3((NPIX + 31) / 32, IN_CH / 32), dim3(32, 8), 0, stream>>>(x, xt);
            psroi_kernel<true><<<mainGrid, 256, 0, stream>>>(xt, regions, conv_w, conv_b, out);
        } else {
            psroi_kernel<false><<<mainGrid, 256, 0, stream>>>(x, regions, conv_w, conv_b, out);
        }
    }
}

// Round 12
// 230.326 us; speedup vs baseline: 1.1189x; 1.0323x over previous
//
#include <hip/hip_runtime.h>
#include <cstddef>

#define IN_CH 1024
#define NT    81
#define KGRID 7
#define NBINS 49
#define HH    100
#define WW    100
#define NPIX  (HH*WW)
#define NREG  1024
#define COLB  82            // gemm column group per bin: 81 real + 1 zero pad
#define NCOL  (NBINS*COLB)  // 4018 gemm columns (32 N-tiles of 128)
#define NPADW 4096          // 32 N-tiles (multiple of 8 XCDs)
#define SBIN  84            // sm per-bin stride in BYTES (int8), 4-aligned rows
#define SROWB (NBINS*SBIN)  // 4116 B per pixel row
#define NG    8             // pool tap-groups per region (8*98 = 784)
#define NSC   2560          // scale table floats (79*32 = 2528 used, padded)
#define PXB   ((NPIX + 31) / 32)        // 313 prep_x col-blocks
#define PXG   (PXB * (IN_CH / 128))     // 2504 prep_x blocks
#define PREPG (PXG + NPADW)             // + 4096 prep_w blocks

typedef unsigned short ushortT;
typedef short bf16x8 __attribute__((ext_vector_type(8)));
typedef float f32x4  __attribute__((ext_vector_type(4)));

static __device__ __forceinline__ unsigned short f2bf(float f) {
    unsigned int u = __builtin_bit_cast(unsigned int, f);
    return (unsigned short)((u + 0x7fffu + ((u >> 16) & 1u)) >> 16);
}

// async global->LDS, 16B per lane; LDS dest = wave-uniform base + lane*16
static __device__ __forceinline__ void gld_lds16(const ushortT* g, ushortT* l) {
    __builtin_amdgcn_global_load_lds(
        (__attribute__((address_space(1))) void*)(unsigned long long)(uintptr_t)g,
        (__attribute__((address_space(3))) void*)(unsigned int)(unsigned long long)(uintptr_t)l,
        16, 0, 0);
}

// ---------- fused prep: x (C,P) fp32 -> xbT (P,C) bf16  |  conv_w -> Wr -------------
__global__ __launch_bounds__(256) void prep_fused(const float* __restrict__ x,
                                                  ushortT* __restrict__ xbT,
                                                  const float* __restrict__ conv_w,
                                                  ushortT* __restrict__ Wr) {
    __shared__ float tile[128][33];
    const int tid = threadIdx.x;
    const int bid = blockIdx.x;
    if (bid < PXG) {
        const int p0 = (bid % PXB) * 32;
        const int c0 = (bid / PXB) * 128;
        const int pl = tid & 31;
        const int cg = tid >> 5;          // 0..7
        const int p = p0 + pl;
#pragma unroll
        for (int it = 0; it < 16; ++it) {
            const int c = it * 8 + cg;
            tile[c][pl] = (p < NPIX) ? x[(size_t)(c0 + c) * NPIX + p] : 0.0f;
        }
        __syncthreads();
#pragma unroll
        for (int pass = 0; pass < 2; ++pass) {
            const int pix = pass * 16 + (tid >> 4);
            const int cb  = (tid & 15) * 8;
            if (p0 + pix < NPIX) {
                uint4 pk;
                pk.x = (unsigned int)f2bf(tile[cb + 0][pix]) | ((unsigned int)f2bf(tile[cb + 1][pix]) << 16);
                pk.y = (unsigned int)f2bf(tile[cb + 2][pix]) | ((unsigned int)f2bf(tile[cb + 3][pix]) << 16);
                pk.z = (unsigned int)f2bf(tile[cb + 4][pix]) | ((unsigned int)f2bf(tile[cb + 5][pix]) << 16);
                pk.w = (unsigned int)f2bf(tile[cb + 6][pix]) | ((unsigned int)f2bf(tile[cb + 7][pix]) << 16);
                *(uint4*)(xbT + (size_t)(p0 + pix) * IN_CH + c0 + cb) = pk;
            }
        }
    } else {
        const int row = bid - PXG;
        const int bin = row / COLB;
        const int t   = row - bin * COLB;
        const int c   = tid * 4;
        uint2 pk; pk.x = 0; pk.y = 0;
        if (bin < NBINS && t < NT) {
            const float4 v = *(const float4*)(conv_w + ((size_t)(t * NBINS + bin)) * IN_CH + c);
            pk.x = (unsigned int)f2bf(v.x) | ((unsigned int)f2bf(v.y) << 16);
            pk.y = (unsigned int)f2bf(v.z) | ((unsigned int)f2bf(v.w) << 16);
        }
        *(uint2*)(Wr + (size_t)row * IN_CH + c) = pk;
    }
}

// ---------- GEMM: sm int8[pix][bin*84+t] x scales[pt*32+nt] ------------------------
// Round-8 proven structure: 128x128 tile, BK=32, global_load_lds w=16, 4 waves (2x2).
// Epilogue: block amax (LDS tree over reused a_lds) -> dynamic int8 quantization.
__global__ __launch_bounds__(256) void gemm_sm(const ushortT* __restrict__ xbT,
                                               const ushortT* __restrict__ Wr,
                                               unsigned char* __restrict__ sm,
                                               float* __restrict__ scales) {
    __shared__ ushortT a_lds[128 * 32];
    __shared__ ushortT b_lds[128 * 32];
    const int tid  = threadIdx.x;
    const int lane = tid & 63;
    const int w    = tid >> 6;
    const int wm   = w & 1;
    const int wn   = w >> 1;
    const int n0   = blockIdx.x * 128;    // nt = blockIdx.x (0..31, mult of 8)
    const int p0   = blockIdx.y * 128;    // pt = blockIdx.y (0..78)

    const int srow0 = w * 32 + (lane >> 2);
    const int scol  = (lane & 3) * 8;
    int ap0 = p0 + srow0;      if (ap0 > NPIX - 1) ap0 = NPIX - 1;
    int ap1 = p0 + srow0 + 16; if (ap1 > NPIX - 1) ap1 = NPIX - 1;
    const ushortT* ag0 = xbT + (size_t)ap0 * IN_CH + scol;
    const ushortT* ag1 = xbT + (size_t)ap1 * IN_CH + scol;
    const ushortT* bg0 = Wr + (size_t)(n0 + srow0) * IN_CH + scol;
    const ushortT* bg1 = Wr + (size_t)(n0 + srow0 + 16) * IN_CH + scol;
    ushortT* al0 = a_lds + (w * 32) * 32;
    ushortT* al1 = a_lds + (w * 32 + 16) * 32;
    ushortT* bl0 = b_lds + (w * 32) * 32;
    ushortT* bl1 = b_lds + (w * 32 + 16) * 32;

    const int m_lane = lane & 15;
    const int k0     = (lane >> 4) * 8;

    f32x4 acc[4][4];
#pragma unroll
    for (int mt = 0; mt < 4; ++mt)
#pragma unroll
        for (int nt = 0; nt < 4; ++nt) acc[mt][nt] = (f32x4){0.f, 0.f, 0.f, 0.f};

    for (int kc = 0; kc < IN_CH / 32; ++kc) {
        __syncthreads();
        gld_lds16(ag0, al0);
        gld_lds16(ag1, al1);
        gld_lds16(bg0, bl0);
        gld_lds16(bg1, bl1);
        ag0 += 32; ag1 += 32; bg0 += 32; bg1 += 32;
        __syncthreads();

        bf16x8 af[4], bf[4];
#pragma unroll
        for (int mt = 0; mt < 4; ++mt)
            af[mt] = *(const bf16x8*)(a_lds + (wm * 64 + mt * 16 + m_lane) * 32 + k0);
#pragma unroll
        for (int nt = 0; nt < 4; ++nt)
            bf[nt] = *(const bf16x8*)(b_lds + (wn * 64 + nt * 16 + m_lane) * 32 + k0);
#pragma unroll
        for (int mt = 0; mt < 4; ++mt)
#pragma unroll
            for (int nt = 0; nt < 4; ++nt)
                acc[mt][nt] = __builtin_amdgcn_mfma_f32_16x16x32_bf16(af[mt], bf[nt], acc[mt][nt], 0, 0, 0);
    }

    // ---- block amax reduction (reuse a_lds as float scratch) ----
    float am = 0.0f;
#pragma unroll
    for (int mt = 0; mt < 4; ++mt)
#pragma unroll
        for (int nt = 0; nt < 4; ++nt)
#pragma unroll
            for (int rg = 0; rg < 4; ++rg)
                am = fmaxf(am, fabsf(acc[mt][nt][rg]));
    __syncthreads();                      // all frag reads done before LDS reuse
    float* red = (float*)a_lds;
    red[tid] = am;
    __syncthreads();
#pragma unroll
    for (int s = 128; s > 0; s >>= 1) {
        if (tid < s) red[tid] = fmaxf(red[tid], red[tid + s]);
        __syncthreads();
    }
    const float amax = fmaxf(red[0], 1e-30f);
    const float inv  = 127.0f / amax;
    if (tid == 0) scales[blockIdx.y * 32 + blockIdx.x] = amax * (1.0f / 127.0f);

    // ---- quantize + store: n = bin*82+t -> byte offset n + 2*(n/82) ----
    const int prow_base = p0 + wm * 64 + (lane >> 4) * 4;
    const int ncol_base = n0 + wn * 64 + m_lane;
    int  coloff[4];
    bool cok[4];
#pragma unroll
    for (int nt = 0; nt < 4; ++nt) {
        const int n = ncol_base + nt * 16;
        cok[nt] = (n < NCOL);
        coloff[nt] = n + 2 * (n / COLB);
    }
#pragma unroll
    for (int mt = 0; mt < 4; ++mt) {
#pragma unroll
        for (int rg = 0; rg < 4; ++rg) {
            const int p = prow_base + mt * 16 + rg;
            if (p < NPIX) {
                unsigned char* rowp = sm + (size_t)p * SROWB;
#pragma unroll
                for (int nt = 0; nt < 4; ++nt)
                    if (cok[nt]) {
                        const int q = __float2int_rn(acc[mt][nt][rg] * inv);
                        rowp[coloff[nt]] = (unsigned char)(signed char)q;
                    }
            }
        }
    }
}

// ---------- pooling: 16B/lane gathers -> 10 taps per wave-load instruction ----------
// lane -> (sub 0..9, cg 0..5): tap row = 6 lanes x uint4 (96B window over 84B row).
// 120-entry padded tap table; 3 prefetched loads/thread; request count cut ~3.4x.
__global__ __launch_bounds__(256) void pool_kernel(const unsigned char* __restrict__ sm,
                                                   const float* __restrict__ scales,
                                                   const float* __restrict__ regions,
                                                   const float* __restrict__ conv_b,
                                                   float* __restrict__ out) {
    __shared__ int   rowo[28]; __shared__ float roww[28];
    __shared__ int   coli[28]; __shared__ float colw[28];
    __shared__ int   pofs[120];
    __shared__ float pw[120];
    __shared__ int   pptb[120];   // (pix>>7)*32
    __shared__ int   pnb[120];    // bin*82
    __shared__ float part[40][100];
    const int tid = threadIdx.x;
    const int r = blockIdx.x;
    const int g = blockIdx.y;   // 0..7

    if (tid < 28) {
        const float4 reg = *(const float4*)(regions + (size_t)r * 4);
        const float top = (reg.x - reg.z * 0.5f) * (float)HH;
        const float bh  = reg.z * ((float)HH / (float)KGRID);
        const int u = tid >> 2, i = tid & 3;
        const int s = i >> 1, hi = i & 1;
        float y = top + ((float)u + ((float)s + 0.5f) * 0.5f) * bh;
        y = fminf(fmaxf(y, 0.0f), (float)(HH - 1));
        const float y0f = floorf(y);
        const int y0 = (int)y0f;
        const float wy1 = y - y0f;
        rowo[tid] = (hi ? min(y0 + 1, HH - 1) : y0) * WW;
        roww[tid] = hi ? wy1 : (1.0f - wy1);
    } else if (tid >= 32 && tid < 60) {
        const float4 reg = *(const float4*)(regions + (size_t)r * 4);
        const float left = (reg.y - reg.w * 0.5f) * (float)WW;
        const float bw   = reg.w * ((float)WW / (float)KGRID);
        const int idx = tid - 32;
        const int v = idx >> 2, j = idx & 3;
        const int s = j >> 1, hi = j & 1;
        float xx = left + ((float)v + ((float)s + 0.5f) * 0.5f) * bw;
        xx = fminf(fmaxf(xx, 0.0f), (float)(WW - 1));
        const float x0f = floorf(xx);
        const int x0 = (int)x0f;
        const float wx1 = xx - x0f;
        coli[idx] = hi ? min(x0 + 1, WW - 1) : x0;
        colw[idx] = hi ? wx1 : (1.0f - wx1);
    }
    __syncthreads();
    if (tid < 120) {
        if (tid < 98) {                     // 8*98 == 784 exactly
            const int tt = g * 98 + tid;
            const int bin = tt >> 4, tap = tt & 15;
            const int u = bin / KGRID, v = bin - u * KGRID;
            const int i = tap >> 2, j = tap & 3;
            const int pix = rowo[u * 4 + i] + coli[v * 4 + j];
            pofs[tid] = pix * SROWB + bin * SBIN;     // BYTE offset, 4-aligned
            pw[tid]   = roww[u * 4 + i] * colw[v * 4 + j] * (1.0f / 196.0f);
            pptb[tid] = (pix >> 7) * 32;
            pnb[tid]  = bin * COLB;
        } else {                             // zero-weight padding taps
            pofs[tid] = 0;
            pw[tid]   = 0.0f;
            pptb[tid] = 0;
            pnb[tid]  = 0;
        }
    }
    __syncthreads();

    const int lane = tid & 63, w = tid >> 6;
    const int sub  = lane / 6;              // 0..9 active, lanes 60..63 idle
    const int cg   = lane - sub * 6;        // 0..5 -> channels cg*16..+15
    if (sub < 10) {
        const int str = w * 10 + sub;       // 0..39
        uint4 v[3];
        // prefetch all 3 taps (16B each) before any use
#pragma unroll
        for (int it = 0; it < 3; ++it)
            v[it] = *(const uint4*)(sm + pofs[it * 40 + str] + cg * 16);

        float acc[16];
#pragma unroll
        for (int ch = 0; ch < 16; ++ch) acc[ch] = 0.0f;
#pragma unroll
        for (int it = 0; it < 3; ++it) {
            const int l  = it * 40 + str;
            const float wt = pw[l];
            const int nb  = pnb[l] + cg * 16;   // n of channel 0
            const int nt0 = nb >> 7;
            const int rr  = nb & 127;
            const float s0 = scales[pptb[l] + nt0];
            const float s1 = scales[pptb[l] + nt0 + 1];
            const float w0 = wt * s0, w1 = wt * s1;
            const unsigned int uu[4] = {v[it].x, v[it].y, v[it].z, v[it].w};
#pragma unroll
            for (int b = 0; b < 4; ++b) {
#pragma unroll
                for (int k = 0; k < 4; ++k) {
                    const int ch = b * 4 + k;
                    const int q = (int)(signed char)((uu[b] >> (k * 8)) & 0xff);
                    acc[ch] += ((rr < 128 - ch) ? w0 : w1) * (float)q;
                }
            }
        }
#pragma unroll
        for (int b = 0; b < 4; ++b) {
            float4 p4;
            p4.x = acc[b * 4]; p4.y = acc[b * 4 + 1];
            p4.z = acc[b * 4 + 2]; p4.w = acc[b * 4 + 3];
            *(float4*)&part[str][cg * 16 + b * 4] = p4;
        }
    }
    __syncthreads();
    if (tid < NT) {
        float vv = 0.f;
#pragma unroll
        for (int s = 0; s < 40; ++s) vv += part[s][tid];
        if (g == 0) {
            float bsum = 0.f;
            for (int bin = 0; bin < NBINS; ++bin) bsum += conv_b[tid * NBINS + bin];
            vv += bsum * (1.0f / (float)NBINS);
        }
        atomicAdd(out + (size_t)r * NT + tid, vv);
    }
}

// =======================  fallback path (round-1 kernel)  ==========================
__global__ __launch_bounds__(256) void xpose_kernel(const float* __restrict__ x,
                                                    float* __restrict__ xt) {
    __shared__ float tile[32][33];
    const int p0 = blockIdx.x * 32;
    const int c0 = blockIdx.y * 32;
    const int tx = threadIdx.x;
    const int ty = threadIdx.y;
#pragma unroll
    for (int k = 0; k < 32; k += 8) {
        const int p = p0 + tx;
        if (p < NPIX) tile[ty + k][tx] = x[(size_t)(c0 + ty + k) * NPIX + p];
    }
    __syncthreads();
#pragma unroll
    for (int k = 0; k < 32; k += 8) {
        const int p = p0 + ty + k;
        if (p < NPIX) xt[(size_t)p * IN_CH + (c0 + tx)] = tile[tx][ty + k];
    }
}

template <bool XPOSED>
__global__ __launch_bounds__(256) void psroi_kernel(
    const float* __restrict__ xsrc, const float* __restrict__ regions,
    const float* __restrict__ conv_w, const float* __restrict__ conv_b,
    float* __restrict__ out) {
    __shared__ float w_lds[32 * 96];
    __shared__ float g_lds[32 * 64];
    __shared__ int   rowoff[64][4];
    __shared__ float rowwf[64][4];
    __shared__ int   colidx[64][4];
    __shared__ float colwf[64][4];
    const int tid = threadIdx.x;
    const int bin = blockIdx.x >> 4;
    const int rg  = blockIdx.x & 15;
    const int u = bin / KGRID, v = bin % KGRID;
    const int r0 = rg * 64;
    if (tid < 64) {
        const float4 reg = *(const float4*)(regions + (size_t)(r0 + tid) * 4);
        const float top  = (reg.x - reg.z * 0.5f) * (float)HH;
        const float left = (reg.y - reg.w * 0.5f) * (float)WW;
        const float bh = reg.z * ((float)HH / (float)KGRID);
        const float bw = reg.w * ((float)WW / (float)KGRID);
        const float scale = 1.0f / 196.0f;
#pragma unroll
        for (int s = 0; s < 2; s++) {
            const float off = (s + 0.5f) * 0.5f;
            float yy = top + ((float)u + off) * bh;
            yy = fminf(fmaxf(yy, 0.0f), (float)(HH - 1));
            const float y0f = floorf(yy);
            const int y0 = (int)y0f;
            const float wy1 = yy - y0f;
            rowoff[tid][2 * s] = y0 * WW;
            rowoff[tid][2 * s + 1] = min(y0 + 1, HH - 1) * WW;
            rowwf[tid][2 * s] = (1.0f - wy1) * scale;
            rowwf[tid][2 * s + 1] = wy1 * scale;
            float xx = left + ((float)v + off) * bw;
            xx = fminf(fmaxf(xx, 0.0f), (float)(WW - 1));
            const float x0f = floorf(xx);
            const int x0 = (int)x0f;
            const float wx1 = xx - x0f;
            colidx[tid][2 * s] = x0;
            colidx[tid][2 * s + 1] = min(x0 + 1, WW - 1);
            colwf[tid][2 * s] = 1.0f - wx1;
            colwf[tid][2 * s + 1] = wx1;
        }
    }
    const int ri = tid & 15, tq = tid >> 4, rb = tid >> 2, cq = tid & 3;
    float acc[4][6];
#pragma unroll
    for (int m = 0; m < 4; m++)
#pragma unroll
        for (int k = 0; k < 6; k++) acc[m][k] = 0.0f;
    for (int chunk = 0; chunk < IN_CH / 32; chunk++) {
        const int c0 = chunk * 32;
        __syncthreads();
#pragma unroll
        for (int it = 0; it < 12; it++) {
            const int idx = it * 256 + tid;
            const int t = idx >> 5, c = idx & 31;
            float val = 0.0f;
            if (t < NT) val = conv_w[(size_t)(t * NBINS + bin) * IN_CH + c0 + c];
            w_lds[c * 96 + t] = val;
        }
        const int cbase = c0 + cq * 8;
        float g8[8];
#pragma unroll
        for (int cc = 0; cc < 8; cc++) g8[cc] = 0.0f;
#pragma unroll
        for (int i = 0; i < 4; i++) {
            const int ro = rowoff[rb][i];
            const float wy = rowwf[rb][i];
#pragma unroll
            for (int j = 0; j < 4; j++) {
                const int pix = ro + colidx[rb][j];
                const float wv = wy * colwf[rb][j];
                if (XPOSED) {
                    const float4* p = (const float4*)(xsrc + (size_t)pix * IN_CH + cbase);
                    const float4 a = p[0]; const float4 b = p[1];
                    g8[0] += wv * a.x; g8[1] += wv * a.y; g8[2] += wv * a.z; g8[3] += wv * a.w;
                    g8[4] += wv * b.x; g8[5] += wv * b.y; g8[6] += wv * b.z; g8[7] += wv * b.w;
                } else {
#pragma unroll
                    for (int cc = 0; cc < 8; cc++)
                        g8[cc] += wv * xsrc[(size_t)(cbase + cc) * NPIX + pix];
                }
            }
        }
#pragma unroll
        for (int cc = 0; cc < 8; cc++) g_lds[(cq * 8 + cc) * 64 + rb] = g8[cc];
        __syncthreads();
#pragma unroll 4
        for (int c = 0; c < 32; c++) {
            float wv[6];
#pragma unroll
            for (int k = 0; k < 6; k++) wv[k] = w_lds[c * 96 + tq * 6 + k];
            const float4 gq = *(const float4*)&g_lds[c * 64 + ri * 4];
            const float gm[4] = {gq.x, gq.y, gq.z, gq.w};
#pragma unroll
            for (int m = 0; m < 4; m++)
#pragma unroll
                for (int k = 0; k < 6; k++) acc[m][k] += gm[m] * wv[k];
        }
    }
    const float invK2 = 1.0f / 49.0f;
#pragma unroll
    for (int k = 0; k < 6; k++) {
        const int t = tq * 6 + k;
        if (t < NT) {
            const float bterm = conv_b[t * NBINS + bin] * invK2;
#pragma unroll
            for (int m = 0; m < 4; m++) {
                const int rr = r0 + ri * 4 + m;
                atomicAdd(&out[(size_t)rr * NT + t], acc[m][k] + bterm);
            }
        }
    }
}

extern "C" void kernel_launch(void* const* d_in, const int* in_sizes, int n_in,
                              void* d_out, int out_size, void* d_ws, size_t ws_size,
                              hipStream_t stream) {
    const float* x       = (const float*)d_in[0];
    const float* regions = (const float*)d_in[1];
    const float* conv_w  = (const float*)d_in[2];
    const float* conv_b  = (const float*)d_in[3];
    float* out = (float*)d_out;

    const size_t sz_xbT = (size_t)NPIX * IN_CH * 2;          // 20,480,000
    const size_t sz_Wr  = (size_t)NPADW * IN_CH * 2;         //  8,388,608
    const size_t sz_sm  = (size_t)NPIX * SROWB + 256;        // 41,160,000 + slack
    const size_t sz_sc  = (size_t)NSC * sizeof(float);       // 10,240
    const size_t need   = sz_xbT + sz_Wr + sz_sm + sz_sc;    // ~70.0 MB

    if (ws_size >= need) {
        ushortT* xbT = (ushortT*)d_ws;
        ushortT* Wr  = (ushortT*)((char*)d_ws + sz_xbT);
        unsigned char* sm = (unsigned char*)d_ws + sz_xbT + sz_Wr;
        float* scales = (float*)((char*)d_ws + sz_xbT + sz_Wr + sz_sm);
        hipMemsetAsync(out, 0, (size_t)out_size * sizeof(float), stream);
        prep_fused<<<dim3(PREPG), 256, 0, stream>>>(x, xbT, conv_w, Wr);
        gemm_sm<<<dim3(NPADW / 128, (NPIX + 127) / 128), 256, 0, stream>>>(xbT, Wr, sm, scales);
        pool_kernel<<<dim3(NREG, NG), 256, 0, stream>>>(sm, scales, regions, conv_b, out);
    } else {
        hipMemsetAsync(out, 0, (size_t)out_size * sizeof(float), stream);
        const size_t xt_bytes = (size_t)NPIX * IN_CH * sizeof(float);
        const dim3 mainGrid(NBINS * 16);
        if (ws_size >= xt_bytes) {
            float* xt = (float*)d_ws;
            xpose_kernel<<<dim3((NPIX + 31) / 32, IN_CH / 32), dim3(32, 8), 0, stream>>>(x, xt);
            psroi_kernel<true><<<mainGrid, 256, 0, stream>>>(xt, regions, conv_w, conv_b, out);
        } else {
            psroi_kernel<false><<<mainGrid, 256, 0, stream>>>(x, regions, conv_w, conv_b, out);
        }
    }
}